// Round 5
// baseline (115.881 us; speedup 1.0000x reference)
//
#include <hip/hip_runtime.h>

#define NH 8
#define LQ 384
#define LK 384
#define BS 2
#define ROWPAD 68   // LDS row stride (64 + 4 pad) -> (17*lane)%32 bank quads, conflict-free b128

// ---------------- Kernel 1: Ek = exp(2*(kW+b1)), layout [bh][k][e] ----------------
// grid = 192: bh = bid/12, 32-k tile = bid%12. Direct coalesced [k][e] writes, no transpose.
__global__ __launch_bounds__(256) void pre_ek_kernel(
    const float* __restrict__ kin, const float* __restrict__ w1,
    const float* __restrict__ b1, float* __restrict__ ws)
{
    const int bid = blockIdx.x;
    const int bh = bid / 12, kt = bid % 12;
    const int b = bh >> 3, h = bh & 7;
    const int k0 = kt * 32;
    const int lane = threadIdx.x & 63, w = threadIdx.x >> 6;

    float w1c[32];                       // w1 k-part column e=lane (coalesced 256B loads)
    const float* w1p = w1 + (size_t)(h * 64 + 32) * 64 + lane;
    #pragma unroll
    for (int d = 0; d < 32; ++d) w1c[d] = w1p[d * 64];
    const float bv = b1[h * 64 + lane];

    #pragma unroll
    for (int s = 0; s < 8; ++s) {
        int kr = w * 8 + s;
        const float* krow = kin + ((size_t)(b * LK + k0 + kr)) * (NH * 32) + h * 32;
        float acc = bv;
        #pragma unroll
        for (int d = 0; d < 32; ++d) acc = __builtin_fmaf(krow[d], w1c[d], acc);
        ws[((size_t)(bh * LK + k0 + kr)) * 64 + lane] = __expf(acc + acc);  // coalesced
    }
}

// ---------------- Kernel 2: Eq + scores (quad-rcp, dbuf pipeline) + softmax + att + PV ----------------
// grid = 768 (3/CU, fully co-resident): bh = blk/48, q-tile of 8; 4 waves, 2 q-rows/wave.
__global__ __launch_bounds__(256) void attn_kernel(
    const float* __restrict__ qin, const float* __restrict__ vin,
    const int* __restrict__ qlens, const int* __restrict__ klens,
    const float* __restrict__ w1, const float* __restrict__ w2g,
    const float* __restrict__ ws,
    float* __restrict__ outg, float* __restrict__ attg)
{
    __shared__ __align__(16) float buf0[64 * ROWPAD];   // 17408B  Ek chunk (even)
    __shared__ __align__(16) float buf1[64 * ROWPAD];   // 17408B  Ek chunk (odd); w1 slice first
    __shared__ __align__(16) float att_s[8][LK];        // 12288B  (front 256 floats: q staging)
    __shared__ __align__(16) float eqs[8 * 64];         // 2048B
    __shared__ __align__(16) float w2s[64];

    const int tid = threadIdx.x, wave = tid >> 6, lane = tid & 63;
    const int bh = blockIdx.x / 48, tile = blockIdx.x % 48;
    const int b = bh >> 3, h = bh & 7;
    const int q0 = tile * 8;
    const int klen = klens[b], qlen = qlens[b];

    const float* ekg = ws + (size_t)bh * LK * 64;

    // ---- stage: w1 q-slice (8KB dense) -> buf1, q-tile -> att_s row0, w2 -> w2s; prefetch c0 ----
    {
        const float4* w1g = (const float4*)(w1 + (size_t)h * 64 * 64);  // d=0..31 => 512 f4
        ((float4*)buf1)[tid]       = w1g[tid];
        ((float4*)buf1)[tid + 256] = w1g[tid + 256];
        if (tid < 64) {
            int r = tid >> 3, c = tid & 7;
            ((float4*)att_s)[tid] =
                ((const float4*)(qin + ((size_t)(b * LQ + q0 + r)) * (NH * 32) + h * 32))[c];
        } else if (tid < 80) {
            ((float4*)w2s)[tid - 64] = ((const float4*)(w2g + h * 64))[tid - 64];
        }
    }
    float4 pf[4];
    {
        const float4* src = (const float4*)ekg;          // chunk 0
        #pragma unroll
        for (int i = 0; i < 4; ++i) pf[i] = src[tid + 256 * i];
    }
    __syncthreads();   // A

    // ---- Eq: rows {wave, wave+4}, e = lane (buf1 + att_s); write chunk0 -> buf0 ----
    {
        const float* qa = (const float*)att_s;
        float a0 = 0.f, a1 = 0.f;
        #pragma unroll
        for (int d = 0; d < 32; ++d) {
            float wv = buf1[d * 64 + lane];
            a0 = __builtin_fmaf(qa[wave * 32 + d],       wv, a0);
            a1 = __builtin_fmaf(qa[(wave + 4) * 32 + d], wv, a1);
        }
        eqs[wave * 64 + lane]       = __expf(a0 + a0);
        eqs[(wave + 4) * 64 + lane] = __expf(a1 + a1);
    }
    #pragma unroll
    for (int i = 0; i < 4; ++i) {
        int f = tid + 256 * i;
        ((float4*)(buf0 + (f >> 4) * ROWPAD))[f & 15] = pf[i];
    }
    {
        const float4* src = (const float4*)(ekg + 1 * 64 * 64);   // chunk 1
        #pragma unroll
        for (int i = 0; i < 4; ++i) pf[i] = src[tid + 256 * i];
    }
    __syncthreads();   // B: eqs + chunk0 visible; buf1 free

    // ---- score loop: 6 chunks of 64 k; thread's k = c*64 + lane ----
    float sc0[6], sc1[6];
    const float4* eq0p = (const float4*)(eqs + (wave * 2 + 0) * 64);
    const float4* eq1p = (const float4*)(eqs + (wave * 2 + 1) * 64);
    #pragma unroll
    for (int c = 0; c < 6; ++c) {
        // 1) write prefetched chunk c+1 into the other buffer
        if (c < 5) {
            float* bufn = (c & 1) ? buf0 : buf1;
            #pragma unroll
            for (int i = 0; i < 4; ++i) {
                int f = tid + 256 * i;
                ((float4*)(bufn + (f >> 4) * ROWPAD))[f & 15] = pf[i];
            }
        }
        // 2) issue loads for chunk c+2
        if (c < 4) {
            const float4* src = (const float4*)(ekg + (size_t)(c + 2) * 64 * 64);
            #pragma unroll
            for (int i = 0; i < 4; ++i) pf[i] = src[tid + 256 * i];
        }
        // 3) compute chunk c
        const float* eb = ((c & 1) ? buf1 : buf0) + lane * ROWPAD;
        float s0 = 0.f, s1 = 0.f;
        #pragma unroll
        for (int e4 = 0; e4 < 16; ++e4) {
            float4 kv = *(const float4*)(eb + 4 * e4);
            float4 wv = ((const float4*)w2s)[e4];
            float4 e0 = eq0p[e4];
            float4 e1 = eq1p[e4];
            {   // row 0: sum_u w_u/(1+Eq_u*Ek_u), one rcp per 4 terms
                float t0 = __builtin_fmaf(e0.x, kv.x, 1.f);
                float t1 = __builtin_fmaf(e0.y, kv.y, 1.f);
                float t2 = __builtin_fmaf(e0.z, kv.z, 1.f);
                float t3 = __builtin_fmaf(e0.w, kv.w, 1.f);
                float p12 = t0 * t1, p34 = t2 * t3;
                float n12 = wv.x * t1; n12 = __builtin_fmaf(wv.y, t0, n12);
                float n34 = wv.z * t3; n34 = __builtin_fmaf(wv.w, t2, n34);
                float num = n12 * p34; num = __builtin_fmaf(n34, p12, num);
                s0 = __builtin_fmaf(num, __builtin_amdgcn_rcpf(p12 * p34), s0);
            }
            {   // row 1
                float t0 = __builtin_fmaf(e1.x, kv.x, 1.f);
                float t1 = __builtin_fmaf(e1.y, kv.y, 1.f);
                float t2 = __builtin_fmaf(e1.z, kv.z, 1.f);
                float t3 = __builtin_fmaf(e1.w, kv.w, 1.f);
                float p12 = t0 * t1, p34 = t2 * t3;
                float n12 = wv.x * t1; n12 = __builtin_fmaf(wv.y, t0, n12);
                float n34 = wv.z * t3; n34 = __builtin_fmaf(wv.w, t2, n34);
                float num = n12 * p34; num = __builtin_fmaf(n34, p12, num);
                s1 = __builtin_fmaf(num, __builtin_amdgcn_rcpf(p12 * p34), s1);
            }
        }
        sc0[c] = s0; sc1[c] = s1;
        if (c < 5) __syncthreads();
    }

    // ---- softmax (score = -2*acc; Sum(w2) shift dropped); att rows -> att_s (wave-private) ----
    #pragma unroll
    for (int i = 0; i < 2; ++i) {
        const float* scp = i ? sc1 : sc0;
        float s_[6], p[6];
        float m = -3.4e38f;
        #pragma unroll
        for (int j = 0; j < 6; ++j) {
            int kk = j * 64 + lane;
            float v = -2.0f * scp[j];
            s_[j] = (kk < klen) ? v : -3.4e38f;
            m = fmaxf(m, s_[j]);
        }
        #pragma unroll
        for (int off = 32; off >= 1; off >>= 1) m = fmaxf(m, __shfl_xor(m, off));
        float ssum = 0.f;
        #pragma unroll
        for (int j = 0; j < 6; ++j) {
            int kk = j * 64 + lane;
            p[j] = (kk < klen) ? __expf(s_[j] - m) : 0.f;
            ssum += p[j];
        }
        #pragma unroll
        for (int off = 32; off >= 1; off >>= 1) ssum += __shfl_xor(ssum, off);
        float inv = __builtin_amdgcn_rcpf(ssum);
        float* arow = att_s[wave * 2 + i];
        #pragma unroll
        for (int j = 0; j < 6; ++j) arow[j * 64 + lane] = p[j] * inv;
    }

    // ---- att global write: coalesced f4 via LDS bounce (same-wave, no barrier) ----
    #pragma unroll
    for (int i3 = 0; i3 < 3; ++i3) {
        int f4i = i3 * 64 + lane;           // 0..191 over 2 rows (96 f4 each)
        int rl = f4i / 96, c4 = f4i % 96;
        float4 av = *(const float4*)(&att_s[wave * 2 + rl][c4 * 4]);
        *(float4*)(attg + ((size_t)(bh * LQ + q0 + wave * 2 + rl)) * LK + c4 * 4) = av;
    }

    // ---- PV: V direct from global (L2-warm), att from wave-private LDS rows ----
    const int kf = lane >> 3, dg = lane & 7;
    const float* vrow = vin + (size_t)b * LK * (NH * 32) + h * 32 + kf * (NH * 32) + dg * 4;
    const float* a0p = att_s[wave * 2 + 0];
    const float* a1p = att_s[wave * 2 + 1];
    float oa[2][4] = {{0.f,0.f,0.f,0.f},{0.f,0.f,0.f,0.f}};
    #pragma unroll 8
    for (int k0 = 0; k0 < LK; k0 += 8) {
        float4 vv = *(const float4*)(vrow + (size_t)k0 * (NH * 32));
        float a0 = a0p[k0 + kf];            // 8-way broadcast, conflict-free
        float a1 = a1p[k0 + kf];
        oa[0][0] = __builtin_fmaf(a0, vv.x, oa[0][0]);
        oa[0][1] = __builtin_fmaf(a0, vv.y, oa[0][1]);
        oa[0][2] = __builtin_fmaf(a0, vv.z, oa[0][2]);
        oa[0][3] = __builtin_fmaf(a0, vv.w, oa[0][3]);
        oa[1][0] = __builtin_fmaf(a1, vv.x, oa[1][0]);
        oa[1][1] = __builtin_fmaf(a1, vv.y, oa[1][1]);
        oa[1][2] = __builtin_fmaf(a1, vv.z, oa[1][2]);
        oa[1][3] = __builtin_fmaf(a1, vv.w, oa[1][3]);
    }
    #pragma unroll
    for (int i = 0; i < 2; ++i)
        #pragma unroll
        for (int u = 0; u < 4; ++u) {
            float x = oa[i][u];
            x += __shfl_xor(x, 8);
            x += __shfl_xor(x, 16);
            x += __shfl_xor(x, 32);
            oa[i][u] = x;
        }
    if (kf == 0) {   // lanes 0..7, dg = lane
        #pragma unroll
        for (int i = 0; i < 2; ++i) {
            int q = q0 + wave * 2 + i;
            float4 o4;
            o4.x = (q < qlen) ? oa[i][0] : 0.f;
            o4.y = (q < qlen) ? oa[i][1] : 0.f;
            o4.z = (q < qlen) ? oa[i][2] : 0.f;
            o4.w = (q < qlen) ? oa[i][3] : 0.f;
            ((float4*)(outg + ((size_t)(b * LQ + q)) * (NH * 32) + h * 32))[dg] = o4;
        }
    }
}

extern "C" void kernel_launch(void* const* d_in, const int* in_sizes, int n_in,
                              void* d_out, int out_size, void* d_ws, size_t ws_size,
                              hipStream_t stream) {
    const float* q    = (const float*)d_in[0];
    const float* k    = (const float*)d_in[1];
    const float* v    = (const float*)d_in[2];
    const int*   qlen = (const int*)d_in[3];
    const int*   klen = (const int*)d_in[4];
    const float* w1   = (const float*)d_in[5];
    const float* b1   = (const float*)d_in[6];
    const float* w2   = (const float*)d_in[7];
    float* out = (float*)d_out;
    float* att = out + (size_t)BS * LQ * NH * 32;   // out: 196608, att: 2359296 floats
    float* ws  = (float*)d_ws;                      // Ek [bh][k][e]: 393216 floats = 1.5 MB

    pre_ek_kernel<<<192, 256, 0, stream>>>(k, w1, b1, ws);
    attn_kernel<<<768, 256, 0, stream>>>(q, v, qlen, klen, w1, w2, ws, out, att);
}

// Round 6
// 105.133 us; speedup vs baseline: 1.1022x; 1.1022x over previous
//
#include <hip/hip_runtime.h>

#define NH 8
#define LQ 384
#define LK 384
#define BS 2

// ---------------- Kernel 1: Ek = exp(2*(kW+b1)), layout [bh][e4][k][4] ----------------
// Quad-interleaved so attn reads one coalesced b128 per (e4, k).
// grid = 192: bh = bid/12, 32-k tile = bid%12.
__global__ __launch_bounds__(256) void pre_ek_kernel(
    const float* __restrict__ kin, const float* __restrict__ w1,
    const float* __restrict__ b1, float* __restrict__ ws)
{
    __shared__ float tile[32][65];
    const int bid = blockIdx.x;
    const int bh = bid / 12, kt = bid % 12;
    const int b = bh >> 3, h = bh & 7;
    const int k0 = kt * 32;
    const int lane = threadIdx.x & 63, w = threadIdx.x >> 6;

    float w1c[32];                       // w1 k-part column e=lane (coalesced 256B loads)
    const float* w1p = w1 + (size_t)(h * 64 + 32) * 64 + lane;
    #pragma unroll
    for (int d = 0; d < 32; ++d) w1c[d] = w1p[d * 64];
    const float bv = b1[h * 64 + lane];

    #pragma unroll
    for (int s = 0; s < 8; ++s) {
        int kr = w * 8 + s;
        const float* krow = kin + ((size_t)(b * LK + k0 + kr)) * (NH * 32) + h * 32;
        float acc = bv;
        #pragma unroll
        for (int d = 0; d < 32; ++d) acc = __builtin_fmaf(krow[d], w1c[d], acc);
        tile[kr][lane] = __expf(acc + acc);
    }
    __syncthreads();
    // 512 float4 to write; 256 threads -> 2 each. f -> (e4 = f>>5, k32 = f&31)
    #pragma unroll
    for (int r = 0; r < 2; ++r) {
        int f = threadIdx.x + r * 256;
        int e4 = f >> 5, k32 = f & 31;
        float4 o;
        o.x = tile[k32][e4 * 4 + 0];
        o.y = tile[k32][e4 * 4 + 1];
        o.z = tile[k32][e4 * 4 + 2];
        o.w = tile[k32][e4 * 4 + 3];
        ((float4*)ws)[((size_t)(bh * 16 + e4)) * LK + k0 + k32] = o;   // coalesced
    }
}

// ---------------- Kernel 2: Eq + scores (quad-rcp, global-Ek, ZERO barriers) ----------------
// grid = 768: bh = blk/48, q-tile of 8; 4 waves, 2 q-rows/wave. All LDS wave-private.
__global__ __launch_bounds__(256) void attn_kernel(
    const float* __restrict__ qin, const float* __restrict__ vin,
    const int* __restrict__ qlens, const int* __restrict__ klens,
    const float* __restrict__ w1, const float* __restrict__ w2g,
    const float* __restrict__ ws,
    float* __restrict__ outg, float* __restrict__ attg)
{
    __shared__ __align__(16) float att_s[8][LK];   // 12288B, rows 2w,2w+1 private to wave w
    __shared__ __align__(16) float eqs[8 * 64];    // 2048B, rows 2w,2w+1 private to wave w
    __shared__ __align__(16) float w2s[4][64];     // 1024B, per-wave copy

    const int tid = threadIdx.x, wave = tid >> 6, lane = tid & 63;
    const int bh = blockIdx.x / 48, tile = blockIdx.x % 48;
    const int b = bh >> 3, h = bh & 7;
    const int q0 = tile * 8;
    const int klen = klens[b], qlen = qlens[b];
    const int r0 = wave * 2;              // this wave's q-rows: q0+r0, q0+r0+1

    // ---- per-wave Eq prologue (no cross-wave data -> no barrier) ----
    {
        const float* w1p = w1 + (size_t)h * 64 * 64 + lane;   // w1[h][d][e=lane], coalesced
        const float* q0p = qin + ((size_t)(b * LQ + q0 + r0)) * (NH * 32) + h * 32;
        const float* q1p = q0p + (NH * 32);
        float a0 = 0.f, a1 = 0.f;
        #pragma unroll
        for (int d = 0; d < 32; ++d) {
            float wv = w1p[d * 64];
            a0 = __builtin_fmaf(q0p[d], wv, a0);   // broadcast load
            a1 = __builtin_fmaf(q1p[d], wv, a1);
        }
        eqs[(r0 + 0) * 64 + lane] = __expf(a0 + a0);
        eqs[(r0 + 1) * 64 + lane] = __expf(a1 + a1);
        w2s[wave][lane] = w2g[h * 64 + lane];
    }
    // same-wave LDS RAW is ordered by lgkmcnt; no __syncthreads needed.

    // ---- score loop: e4 outer (eq/w2 in regs), k-chunk inner; Ek via coalesced global b128 ----
    float sc0[6] = {0.f,0.f,0.f,0.f,0.f,0.f};
    float sc1[6] = {0.f,0.f,0.f,0.f,0.f,0.f};
    const float4* ekq  = (const float4*)ws + ((size_t)bh * 16) * LK + lane;  // + e4*384 + c*64
    const float4* eq0p = (const float4*)(eqs + (r0 + 0) * 64);
    const float4* eq1p = (const float4*)(eqs + (r0 + 1) * 64);
    const float4* w2p  = (const float4*)(&w2s[wave][0]);

    #pragma unroll 4
    for (int e4 = 0; e4 < 16; ++e4) {
        float4 e0 = eq0p[e4];
        float4 e1 = eq1p[e4];
        float4 wv = w2p[e4];
        const float4* kp = ekq + e4 * LK;
        #pragma unroll
        for (int c = 0; c < 6; ++c) {
            float4 kv = kp[c * 64];
            {   // row 0: sum_u w_u/(1+Eq_u*Ek_u), one rcp per 4 terms
                float t0 = __builtin_fmaf(e0.x, kv.x, 1.f);
                float t1 = __builtin_fmaf(e0.y, kv.y, 1.f);
                float t2 = __builtin_fmaf(e0.z, kv.z, 1.f);
                float t3 = __builtin_fmaf(e0.w, kv.w, 1.f);
                float p12 = t0 * t1, p34 = t2 * t3;
                float n12 = wv.x * t1; n12 = __builtin_fmaf(wv.y, t0, n12);
                float n34 = wv.z * t3; n34 = __builtin_fmaf(wv.w, t2, n34);
                float num = n12 * p34; num = __builtin_fmaf(n34, p12, num);
                sc0[c] = __builtin_fmaf(num, __builtin_amdgcn_rcpf(p12 * p34), sc0[c]);
            }
            {   // row 1
                float t0 = __builtin_fmaf(e1.x, kv.x, 1.f);
                float t1 = __builtin_fmaf(e1.y, kv.y, 1.f);
                float t2 = __builtin_fmaf(e1.z, kv.z, 1.f);
                float t3 = __builtin_fmaf(e1.w, kv.w, 1.f);
                float p12 = t0 * t1, p34 = t2 * t3;
                float n12 = wv.x * t1; n12 = __builtin_fmaf(wv.y, t0, n12);
                float n34 = wv.z * t3; n34 = __builtin_fmaf(wv.w, t2, n34);
                float num = n12 * p34; num = __builtin_fmaf(n34, p12, num);
                sc1[c] = __builtin_fmaf(num, __builtin_amdgcn_rcpf(p12 * p34), sc1[c]);
            }
        }
    }

    // ---- softmax (score = -2*acc; Sum(w2) shift dropped); att -> global (coalesced b32) + att_s ----
    #pragma unroll
    for (int i = 0; i < 2; ++i) {
        const float* scp = i ? sc1 : sc0;
        int q = q0 + r0 + i;
        float s_[6], p[6];
        float m = -3.4e38f;
        #pragma unroll
        for (int j = 0; j < 6; ++j) {
            int kk = j * 64 + lane;
            float v = -2.0f * scp[j];
            s_[j] = (kk < klen) ? v : -3.4e38f;
            m = fmaxf(m, s_[j]);
        }
        #pragma unroll
        for (int off = 32; off >= 1; off >>= 1) m = fmaxf(m, __shfl_xor(m, off));
        float ssum = 0.f;
        #pragma unroll
        for (int j = 0; j < 6; ++j) {
            int kk = j * 64 + lane;
            p[j] = (kk < klen) ? __expf(s_[j] - m) : 0.f;
            ssum += p[j];
        }
        #pragma unroll
        for (int off = 32; off >= 1; off >>= 1) ssum += __shfl_xor(ssum, off);
        float inv = __builtin_amdgcn_rcpf(ssum);
        float* arow = att_s[r0 + i];
        float* ag = attg + ((size_t)(bh * LQ + q)) * LK;
        #pragma unroll
        for (int j = 0; j < 6; ++j) {
            float a = p[j] * inv;
            arow[j * 64 + lane] = a;
            ag[j * 64 + lane]   = a;
        }
    }

    // ---- PV: V direct from global (L2/L1-warm), att from wave-private LDS rows ----
    const int kf = lane >> 3, dg = lane & 7;
    const float* vrow = vin + (size_t)b * LK * (NH * 32) + h * 32 + kf * (NH * 32) + dg * 4;
    const float* a0p = att_s[r0 + 0];
    const float* a1p = att_s[r0 + 1];
    float oa[2][4] = {{0.f,0.f,0.f,0.f},{0.f,0.f,0.f,0.f}};
    #pragma unroll 8
    for (int k0 = 0; k0 < LK; k0 += 8) {
        float4 vv = *(const float4*)(vrow + (size_t)k0 * (NH * 32));
        float a0 = a0p[k0 + kf];            // 8-way broadcast, conflict-free
        float a1 = a1p[k0 + kf];
        oa[0][0] = __builtin_fmaf(a0, vv.x, oa[0][0]);
        oa[0][1] = __builtin_fmaf(a0, vv.y, oa[0][1]);
        oa[0][2] = __builtin_fmaf(a0, vv.z, oa[0][2]);
        oa[0][3] = __builtin_fmaf(a0, vv.w, oa[0][3]);
        oa[1][0] = __builtin_fmaf(a1, vv.x, oa[1][0]);
        oa[1][1] = __builtin_fmaf(a1, vv.y, oa[1][1]);
        oa[1][2] = __builtin_fmaf(a1, vv.z, oa[1][2]);
        oa[1][3] = __builtin_fmaf(a1, vv.w, oa[1][3]);
    }
    #pragma unroll
    for (int i = 0; i < 2; ++i)
        #pragma unroll
        for (int u = 0; u < 4; ++u) {
            float x = oa[i][u];
            x += __shfl_xor(x, 8);
            x += __shfl_xor(x, 16);
            x += __shfl_xor(x, 32);
            oa[i][u] = x;
        }
    if (kf == 0) {   // lanes 0..7, dg = lane
        #pragma unroll
        for (int i = 0; i < 2; ++i) {
            int q = q0 + r0 + i;
            float4 o4;
            o4.x = (q < qlen) ? oa[i][0] : 0.f;
            o4.y = (q < qlen) ? oa[i][1] : 0.f;
            o4.z = (q < qlen) ? oa[i][2] : 0.f;
            o4.w = (q < qlen) ? oa[i][3] : 0.f;
            ((float4*)(outg + ((size_t)(b * LQ + q)) * (NH * 32) + h * 32))[dg] = o4;
        }
    }
}

extern "C" void kernel_launch(void* const* d_in, const int* in_sizes, int n_in,
                              void* d_out, int out_size, void* d_ws, size_t ws_size,
                              hipStream_t stream) {
    const float* q    = (const float*)d_in[0];
    const float* k    = (const float*)d_in[1];
    const float* v    = (const float*)d_in[2];
    const int*   qlen = (const int*)d_in[3];
    const int*   klen = (const int*)d_in[4];
    const float* w1   = (const float*)d_in[5];
    const float* b1   = (const float*)d_in[6];
    const float* w2   = (const float*)d_in[7];
    float* out = (float*)d_out;
    float* att = out + (size_t)BS * LQ * NH * 32;   // out: 196608, att: 2359296 floats
    float* ws  = (float*)d_ws;                      // Ek [bh][e4][k][4]: 393216 floats = 1.5 MB

    pre_ek_kernel<<<192, 256, 0, stream>>>(k, w1, b1, ws);
    attn_kernel<<<768, 256, 0, stream>>>(q, v, qlen, klen, w1, w2, ws, out, att);
}

// Round 7
// 100.824 us; speedup vs baseline: 1.1493x; 1.0427x over previous
//
#include <hip/hip_runtime.h>

#define NH 8
#define LQ 384
#define LK 384
#define BS 2

// ---------------- Kernel 1: Ek = exp(2*(kW+b1)), layout [bh][e4][k][4] ----------------
// Quad-interleaved so attn reads one coalesced b128 per (e4, k).
__global__ __launch_bounds__(256) void pre_ek_kernel(
    const float* __restrict__ kin, const float* __restrict__ w1,
    const float* __restrict__ b1, float* __restrict__ ws)
{
    __shared__ float tile[32][65];
    const int bid = blockIdx.x;
    const int bh = bid / 12, kt = bid % 12;
    const int b = bh >> 3, h = bh & 7;
    const int k0 = kt * 32;
    const int lane = threadIdx.x & 63, w = threadIdx.x >> 6;

    float w1c[32];
    const float* w1p = w1 + (size_t)(h * 64 + 32) * 64 + lane;
    #pragma unroll
    for (int d = 0; d < 32; ++d) w1c[d] = w1p[d * 64];
    const float bv = b1[h * 64 + lane];

    #pragma unroll
    for (int s = 0; s < 8; ++s) {
        int kr = w * 8 + s;
        const float* krow = kin + ((size_t)(b * LK + k0 + kr)) * (NH * 32) + h * 32;
        float acc = bv;
        #pragma unroll
        for (int d = 0; d < 32; ++d) acc = __builtin_fmaf(krow[d], w1c[d], acc);
        tile[kr][lane] = __expf(acc + acc);
    }
    __syncthreads();
    #pragma unroll
    for (int r = 0; r < 2; ++r) {
        int f = threadIdx.x + r * 256;
        int e4 = f >> 5, k32 = f & 31;
        float4 o;
        o.x = tile[k32][e4 * 4 + 0];
        o.y = tile[k32][e4 * 4 + 1];
        o.z = tile[k32][e4 * 4 + 2];
        o.w = tile[k32][e4 * 4 + 3];
        ((float4*)ws)[((size_t)(bh * 16 + e4)) * LK + k0 + k32] = o;
    }
}

// ---------------- Kernel 2: q-tile=4, wave=(row-pair, k-half); 24 waves/CU ----------------
// grid = 1536: bh = blk/96, tile = blk%96 (4 q-rows). Wave w: rows {2p,2p+1}, k-half hh.
__global__ __launch_bounds__(256) void attn_kernel(
    const float* __restrict__ qin, const float* __restrict__ vin,
    const int* __restrict__ qlens, const int* __restrict__ klens,
    const float* __restrict__ w1, const float* __restrict__ w2g,
    const float* __restrict__ ws,
    float* __restrict__ outg, float* __restrict__ attg)
{
    __shared__ __align__(16) float eqs[4 * 64];        // 1KB: Eq rows 0..3
    __shared__ __align__(16) float att_h[4][2 * 192];  // 6KB: wave-private att halves
    __shared__ __align__(16) float w2s[64];
    __shared__ float smx[2][2][2];                     // [pair][row][half] partial max
    __shared__ float ssm[2][2][2];                     // partial sums
    __shared__ __align__(16) float4 pvp[2][2][2][8];   // [pair][half][row][dvq] PV partials

    const int tid = threadIdx.x, wave = tid >> 6, lane = tid & 63;
    const int pair = wave >> 1, hh = wave & 1;
    const int bh = blockIdx.x / 96, tile = blockIdx.x % 96;
    const int b = bh >> 3, h = bh & 7;
    const int q0 = tile * 4;
    const int klen = klens[b], qlen = qlens[b];

    // ---- Eq: wave w computes row w (e = lane) ----
    {
        const float* w1p = w1 + (size_t)h * 64 * 64 + lane;   // coalesced columns
        const float* qp  = qin + ((size_t)(b * LQ + q0 + wave)) * (NH * 32) + h * 32;
        float a = 0.f;
        #pragma unroll
        for (int d = 0; d < 32; ++d) a = __builtin_fmaf(qp[d], w1p[d * 64], a);
        eqs[wave * 64 + lane] = __expf(a + a);
        if (wave == 0) w2s[lane] = w2g[h * 64 + lane];
    }
    __syncthreads();   // (1) eqs + w2s visible

    // ---- score: k = hh*192 + c*64 + lane, c in 0..2; reg-dbuf on kv ----
    float sc0[3] = {0.f, 0.f, 0.f};
    float sc1[3] = {0.f, 0.f, 0.f};
    const float4* ekq  = (const float4*)ws + ((size_t)bh * 16) * LK + hh * 192 + lane;
    const float4* eq0p = (const float4*)(eqs + (2 * pair) * 64);
    const float4* eq1p = (const float4*)(eqs + (2 * pair + 1) * 64);
    const float4* w2p  = (const float4*)w2s;

    float4 kv[3];
    #pragma unroll
    for (int c = 0; c < 3; ++c) kv[c] = ekq[c * 64];

    #pragma unroll
    for (int e4 = 0; e4 < 16; ++e4) {
        float4 nkv[3];
        if (e4 < 15) {
            const float4* np = ekq + (size_t)(e4 + 1) * LK;
            #pragma unroll
            for (int c = 0; c < 3; ++c) nkv[c] = np[c * 64];
        }
        float4 e0 = eq0p[e4];   // ds_read_b128 broadcast
        float4 e1 = eq1p[e4];
        float4 wv = w2p[e4];
        #pragma unroll
        for (int c = 0; c < 3; ++c) {
            float4 kq = kv[c];
            {   // row 0: sum_u w_u/(1+Eq_u*Ek_u), one rcp per 4 terms
                float t0 = __builtin_fmaf(e0.x, kq.x, 1.f);
                float t1 = __builtin_fmaf(e0.y, kq.y, 1.f);
                float t2 = __builtin_fmaf(e0.z, kq.z, 1.f);
                float t3 = __builtin_fmaf(e0.w, kq.w, 1.f);
                float p12 = t0 * t1, p34 = t2 * t3;
                float n12 = wv.x * t1; n12 = __builtin_fmaf(wv.y, t0, n12);
                float n34 = wv.z * t3; n34 = __builtin_fmaf(wv.w, t2, n34);
                float num = n12 * p34; num = __builtin_fmaf(n34, p12, num);
                sc0[c] = __builtin_fmaf(num, __builtin_amdgcn_rcpf(p12 * p34), sc0[c]);
            }
            {   // row 1
                float t0 = __builtin_fmaf(e1.x, kq.x, 1.f);
                float t1 = __builtin_fmaf(e1.y, kq.y, 1.f);
                float t2 = __builtin_fmaf(e1.z, kq.z, 1.f);
                float t3 = __builtin_fmaf(e1.w, kq.w, 1.f);
                float p12 = t0 * t1, p34 = t2 * t3;
                float n12 = wv.x * t1; n12 = __builtin_fmaf(wv.y, t0, n12);
                float n34 = wv.z * t3; n34 = __builtin_fmaf(wv.w, t2, n34);
                float num = n12 * p34; num = __builtin_fmaf(n34, p12, num);
                sc1[c] = __builtin_fmaf(num, __builtin_amdgcn_rcpf(p12 * p34), sc1[c]);
            }
        }
        if (e4 < 15) {
            #pragma unroll
            for (int c = 0; c < 3; ++c) kv[c] = nkv[c];
        }
    }

    // ---- softmax across the two k-half waves (score = -2*acc) ----
    float s0_[3], s1_[3];
    float m0 = -3.4e38f, m1 = -3.4e38f;
    #pragma unroll
    for (int c = 0; c < 3; ++c) {
        int kk = hh * 192 + c * 64 + lane;
        s0_[c] = (kk < klen) ? -2.0f * sc0[c] : -3.4e38f;
        s1_[c] = (kk < klen) ? -2.0f * sc1[c] : -3.4e38f;
        m0 = fmaxf(m0, s0_[c]);
        m1 = fmaxf(m1, s1_[c]);
    }
    #pragma unroll
    for (int off = 32; off >= 1; off >>= 1) {
        m0 = fmaxf(m0, __shfl_xor(m0, off));
        m1 = fmaxf(m1, __shfl_xor(m1, off));
    }
    if (lane == 0) { smx[pair][0][hh] = m0; smx[pair][1][hh] = m1; }
    __syncthreads();   // (2)
    m0 = fmaxf(smx[pair][0][0], smx[pair][0][1]);
    m1 = fmaxf(smx[pair][1][0], smx[pair][1][1]);

    float p0[3], p1[3];
    float u0 = 0.f, u1 = 0.f;
    #pragma unroll
    for (int c = 0; c < 3; ++c) {
        int kk = hh * 192 + c * 64 + lane;
        p0[c] = (kk < klen) ? __expf(s0_[c] - m0) : 0.f;
        p1[c] = (kk < klen) ? __expf(s1_[c] - m1) : 0.f;
        u0 += p0[c];
        u1 += p1[c];
    }
    #pragma unroll
    for (int off = 32; off >= 1; off >>= 1) {
        u0 += __shfl_xor(u0, off);
        u1 += __shfl_xor(u1, off);
    }
    if (lane == 0) { ssm[pair][0][hh] = u0; ssm[pair][1][hh] = u1; }
    __syncthreads();   // (3)
    float inv0 = __builtin_amdgcn_rcpf(ssm[pair][0][0] + ssm[pair][0][1]);
    float inv1 = __builtin_amdgcn_rcpf(ssm[pair][1][0] + ssm[pair][1][1]);

    // ---- att halves -> wave-private LDS (same-wave RAW, no barrier) ----
    {
        float* ar = att_h[wave];
        #pragma unroll
        for (int c = 0; c < 3; ++c) {
            ar[c * 64 + lane]       = p0[c] * inv0;
            ar[192 + c * 64 + lane] = p1[c] * inv1;
        }
    }

    // ---- PV over own k-half: lane = kf*8 + dg ----
    const int kf = lane >> 3, dg = lane & 7;
    const float* vbase = vin + (size_t)b * LK * (NH * 32) + h * 32
                       + (size_t)(hh * 192 + kf) * (NH * 32) + dg * 4;
    const float* a0p = att_h[wave];
    const float* a1p = att_h[wave] + 192;
    float oa0[4] = {0.f,0.f,0.f,0.f}, oa1[4] = {0.f,0.f,0.f,0.f};
    #pragma unroll 8
    for (int k0 = 0; k0 < 192; k0 += 8) {
        float4 vv = *(const float4*)(vbase + (size_t)k0 * (NH * 32));
        float a0 = a0p[k0 + kf];   // broadcast, conflict-free
        float a1 = a1p[k0 + kf];
        oa0[0] = __builtin_fmaf(a0, vv.x, oa0[0]);
        oa0[1] = __builtin_fmaf(a0, vv.y, oa0[1]);
        oa0[2] = __builtin_fmaf(a0, vv.z, oa0[2]);
        oa0[3] = __builtin_fmaf(a0, vv.w, oa0[3]);
        oa1[0] = __builtin_fmaf(a1, vv.x, oa1[0]);
        oa1[1] = __builtin_fmaf(a1, vv.y, oa1[1]);
        oa1[2] = __builtin_fmaf(a1, vv.z, oa1[2]);
        oa1[3] = __builtin_fmaf(a1, vv.w, oa1[3]);
    }
    #pragma unroll
    for (int u = 0; u < 4; ++u) {
        oa0[u] += __shfl_xor(oa0[u], 8);
        oa0[u] += __shfl_xor(oa0[u], 16);
        oa0[u] += __shfl_xor(oa0[u], 32);
        oa1[u] += __shfl_xor(oa1[u], 8);
        oa1[u] += __shfl_xor(oa1[u], 16);
        oa1[u] += __shfl_xor(oa1[u], 32);
    }
    if (kf == 0) {   // lanes 0..7, dg = lane
        pvp[pair][hh][0][dg] = make_float4(oa0[0], oa0[1], oa0[2], oa0[3]);
        pvp[pair][hh][1][dg] = make_float4(oa1[0], oa1[1], oa1[2], oa1[3]);
    }
    __syncthreads();   // (4) LDS-only wait (att stores deferred)

    // ---- combine PV halves: wave w -> row w; lanes 0..7 ----
    if (lane < 8) {
        int q = q0 + wave;
        float4 xa = pvp[wave >> 1][0][wave & 1][lane];
        float4 xb = pvp[wave >> 1][1][wave & 1][lane];
        float4 o4;
        bool ok = (q < qlen);
        o4.x = ok ? (xa.x + xb.x) : 0.f;
        o4.y = ok ? (xa.y + xb.y) : 0.f;
        o4.z = ok ? (xa.z + xb.z) : 0.f;
        o4.w = ok ? (xa.w + xb.w) : 0.f;
        ((float4*)(outg + ((size_t)(b * LQ + q)) * (NH * 32) + h * 32))[lane] = o4;
    }

    // ---- deferred global att writes (coalesced b32, from regs) ----
    {
        float* ag = attg + ((size_t)(bh * LQ + q0 + 2 * pair)) * LK + hh * 192;
        #pragma unroll
        for (int c = 0; c < 3; ++c) ag[c * 64 + lane] = p0[c] * inv0;
        ag += LK;
        #pragma unroll
        for (int c = 0; c < 3; ++c) ag[c * 64 + lane] = p1[c] * inv1;
    }
}

extern "C" void kernel_launch(void* const* d_in, const int* in_sizes, int n_in,
                              void* d_out, int out_size, void* d_ws, size_t ws_size,
                              hipStream_t stream) {
    const float* q    = (const float*)d_in[0];
    const float* k    = (const float*)d_in[1];
    const float* v    = (const float*)d_in[2];
    const int*   qlen = (const int*)d_in[3];
    const int*   klen = (const int*)d_in[4];
    const float* w1   = (const float*)d_in[5];
    const float* b1   = (const float*)d_in[6];
    const float* w2   = (const float*)d_in[7];
    float* out = (float*)d_out;
    float* att = out + (size_t)BS * LQ * NH * 32;   // out: 196608, att: 2359296 floats
    float* ws  = (float*)d_ws;                      // Ek [bh][e4][k][4]: 1.5 MB

    pre_ek_kernel<<<192, 256, 0, stream>>>(k, w1, b1, ws);
    attn_kernel<<<1536, 256, 0, stream>>>(q, v, qlen, klen, w1, w2, ws, out, att);
}